// Round 9
// baseline (104.608 us; speedup 1.0000x reference)
//
#include <hip/hip_runtime.h>
#include <hip/hip_bf16.h>

typedef float f32x4 __attribute__((ext_vector_type(4)));
typedef __bf16 bf16x8 __attribute__((ext_vector_type(8)));
typedef unsigned short u16;

// Problem dims (fixed): B=128, T=64, H=1024, Hu=512, J=129, N=128, I=64, MJW=64
// ws layout
#define OFF_W1B  0u            // 512x1024 bf16 fragment-order = 1048576 B
#define OFF_W23B 1048576u      // 144x512 bf16 fragment-order = 147456 B
#define OFF_TS   1196032u      // 8192x512 bf16 = 8388608 B
#define OFF_JWT  9584640u      // 128 x 64(col) x 64(row) f32 = 2097152 B
#define OFF_P0   11681792u     // 8192 f32 = 32768 B

static __device__ __forceinline__ u16 f2bf(float x) {
    __bf16 h = (__bf16)x;
    return __builtin_bit_cast(u16, h);
}

// ---------------------------------------------------------------------------
// prep: blocks 0..255: W1(1024x512 f32) -> W1B bf16 in MFMA fragment order:
//         W1B[((kt*32+ct)*64 + lg*16+lr)*8 + j] = W1[k=kt*32+lg*8+j][n=ct*16+lr]
//       blocks 256..291: W2/W3 -> W23B fragment order (as before)
// ---------------------------------------------------------------------------
__global__ __launch_bounds__(256) void prep_kernel(
    const float* __restrict__ W1, const float* __restrict__ W2,
    const float* __restrict__ W3,
    __bf16* __restrict__ W1B, __bf16* __restrict__ W23B)
{
    const int t = threadIdx.x;
    if (blockIdx.x < 256) {
        int g = blockIdx.x * 256 + t;        // 0..65535
        int n = g & 511, k8 = g >> 9;        // k8 = 0..127
        bf16x8 v;
        #pragma unroll
        for (int j = 0; j < 8; ++j)
            v[j] = (__bf16)W1[(size_t)(k8 * 8 + j) * 512 + n];   // coalesced per j
        int kt = k8 >> 2, lg = k8 & 3, ct = n >> 4, lr = n & 15;
        *(bf16x8*)&W1B[(((size_t)(kt * 32 + ct)) * 64 + lg * 16 + lr) * 8] = v;
    } else {
        int g = (blockIdx.x - 256) * 256 + t;   // 0..9215
        if (g < 9216) {
            int n = g >> 6;            // 0..143
            int k8 = (g & 63) * 8;     // 0,8,..,504
            bf16x8 v;
            #pragma unroll
            for (int j = 0; j < 8; ++j) {
                int k = k8 + j;
                float x = 0.0f;
                if (n < 129) x = W2[(size_t)k * 129 + n];
                else if (n == 129) x = W3[k];
                v[j] = (__bf16)x;
            }
            int kk = k8 >> 5, lg = (k8 >> 3) & 3, ct = n >> 4, lr = n & 15;
            *(bf16x8*)&W23B[(((size_t)(kk * 9 + ct)) * 64 + lg * 16 + lr) * 8] = v;
        }
    }
}

// ---------------------------------------------------------------------------
// GEMM1 v2: ts = tanh(Y @ W1 + b1). NO LDS, NO barriers. B streamed from
// fragment-ordered W1B (coalesced 16B/lane, L2-hot); A-fragments loaded as
// f32 direct from Y and converted in-register. Pure vmcnt dataflow pipeline.
// Tile 64x128, 4 waves (2x2), wave tile 32x64. Grid (128,4).
// ---------------------------------------------------------------------------
__global__ __launch_bounds__(256) void gemm1_kernel(
    const float* __restrict__ Y, const u16* __restrict__ W1B,
    const float* __restrict__ b1, u16* __restrict__ ts)
{
    const int tid = threadIdx.x;
    const int m0 = blockIdx.x * 64, nb = blockIdx.y;   // n0 = nb*128
    const int wid = tid >> 6, lane = tid & 63;
    const int wr = wid >> 1, wc = wid & 1;
    const int lr = lane & 15, lg = lane >> 4;

    const float* ya0 = Y + (size_t)(m0 + wr * 32 + lr) * 1024 + lg * 8;        // m-tile 0
    const float* ya1 = ya0 + (size_t)16 * 1024;                                 // m-tile 1
    const int ct0 = nb * 8 + wc * 4;
    const u16* wb = W1B + ((size_t)ct0 * 64 + lane) * 8;

    f32x4 acc[2][4];
    #pragma unroll
    for (int m = 0; m < 2; m++)
        #pragma unroll
        for (int n = 0; n < 4; n++) { f32x4 z = {0.f,0.f,0.f,0.f}; acc[m][n] = z; }

    #pragma unroll 4
    for (int kt = 0; kt < 32; ++kt) {
        float4 p0v = *(const float4*)(ya0 + kt * 32);
        float4 p1v = *(const float4*)(ya0 + kt * 32 + 4);
        float4 q0v = *(const float4*)(ya1 + kt * 32);
        float4 q1v = *(const float4*)(ya1 + kt * 32 + 4);
        bf16x8 a0, a1;
        a0[0]=(__bf16)p0v.x; a0[1]=(__bf16)p0v.y; a0[2]=(__bf16)p0v.z; a0[3]=(__bf16)p0v.w;
        a0[4]=(__bf16)p1v.x; a0[5]=(__bf16)p1v.y; a0[6]=(__bf16)p1v.z; a0[7]=(__bf16)p1v.w;
        a1[0]=(__bf16)q0v.x; a1[1]=(__bf16)q0v.y; a1[2]=(__bf16)q0v.z; a1[3]=(__bf16)q0v.w;
        a1[4]=(__bf16)q1v.x; a1[5]=(__bf16)q1v.y; a1[6]=(__bf16)q1v.z; a1[7]=(__bf16)q1v.w;
        const u16* wk = wb + (size_t)kt * 16384;     // kt*32*64*8
        bf16x8 bf0 = *(const bf16x8*)(wk);
        bf16x8 bf1 = *(const bf16x8*)(wk + 512);
        bf16x8 bf2 = *(const bf16x8*)(wk + 1024);
        bf16x8 bf3 = *(const bf16x8*)(wk + 1536);
        acc[0][0] = __builtin_amdgcn_mfma_f32_16x16x32_bf16(a0, bf0, acc[0][0], 0, 0, 0);
        acc[0][1] = __builtin_amdgcn_mfma_f32_16x16x32_bf16(a0, bf1, acc[0][1], 0, 0, 0);
        acc[0][2] = __builtin_amdgcn_mfma_f32_16x16x32_bf16(a0, bf2, acc[0][2], 0, 0, 0);
        acc[0][3] = __builtin_amdgcn_mfma_f32_16x16x32_bf16(a0, bf3, acc[0][3], 0, 0, 0);
        acc[1][0] = __builtin_amdgcn_mfma_f32_16x16x32_bf16(a1, bf0, acc[1][0], 0, 0, 0);
        acc[1][1] = __builtin_amdgcn_mfma_f32_16x16x32_bf16(a1, bf1, acc[1][1], 0, 0, 0);
        acc[1][2] = __builtin_amdgcn_mfma_f32_16x16x32_bf16(a1, bf2, acc[1][2], 0, 0, 0);
        acc[1][3] = __builtin_amdgcn_mfma_f32_16x16x32_bf16(a1, bf3, acc[1][3], 0, 0, 0);
    }

    // epilogue: bias + tanh + bf16 store
    #pragma unroll
    for (int m = 0; m < 2; m++) {
        #pragma unroll
        for (int n = 0; n < 4; n++) {
            int col = nb * 128 + wc * 64 + n * 16 + lr;
            float bias = b1[col];
            #pragma unroll
            for (int j = 0; j < 4; j++) {
                int row = m0 + wr * 32 + m * 16 + lg * 4 + j;
                float v = tanhf(acc[m][n][j] + bias);
                ts[(size_t)row * 512 + col] = f2bf(v);
            }
        }
    }
}

// ---------------------------------------------------------------------------
// band: GEMM2 + softmax + sigmoid only. One block = one batch (4 waves).
// Writes pre-shifted TRANSPOSED band jwT[b][c][k] = M_b[k][c] and p0.
// ---------------------------------------------------------------------------
__global__ __launch_bounds__(256) void band_kernel(
    const u16* __restrict__ ts, const u16* __restrict__ W23B,
    const float* __restrict__ b2, const float* __restrict__ b3,
    float* __restrict__ jwT, float* __restrict__ p0)
{
    const int b = blockIdx.x;
    const int tid = threadIdx.x;
    const int w = tid >> 6, lane = tid & 63;
    const int lr = lane & 15, lg = lane >> 4;
    const int r0 = b * 64 + w * 16;

    f32x4 acc[9];
    #pragma unroll
    for (int ct = 0; ct < 9; ct++) { f32x4 z = {0.f,0.f,0.f,0.f}; acc[ct] = z; }

    #pragma unroll 4
    for (int kk = 0; kk < 16; ++kk) {
        bf16x8 a = *(const bf16x8*)(ts + (size_t)(r0 + lr) * 512 + kk * 32 + lg * 8);
        #pragma unroll
        for (int ct = 0; ct < 9; ct++) {
            bf16x8 bv = *(const bf16x8*)(W23B + ((size_t)(kk * 9 + ct) * 64 + lane) * 8);
            acc[ct] = __builtin_amdgcn_mfma_f32_16x16x32_bf16(a, bv, acc[ct], 0, 0, 0);
        }
    }

    float b3v = b3[0];
    #pragma unroll
    for (int j = 0; j < 4; j++) {
        int rloc = w * 16 + lg * 4 + j;   // row within batch (0..63)
        float v[9];
        float mx = -1e30f;
        #pragma unroll
        for (int ct = 0; ct < 9; ct++) {
            int col = ct * 16 + lr;
            if (col < 129) { float x = acc[ct][j] + b2[col]; v[ct] = x; mx = fmaxf(mx, x); }
            else v[ct] = -1e30f;
        }
        #pragma unroll
        for (int o = 1; o < 16; o <<= 1) mx = fmaxf(mx, __shfl_xor(mx, o));
        float sum = 0.f;
        #pragma unroll
        for (int ct = 0; ct < 9; ct++) {
            int col = ct * 16 + lr;
            if (col < 129) { float e = expf(v[ct] - mx); v[ct] = e; sum += e; }
        }
        #pragma unroll
        for (int o = 1; o < 16; o <<= 1) sum += __shfl_xor(sum, o);
        float inv = 1.0f / sum;
        #pragma unroll
        for (int ct = 0; ct < 9; ct++) {
            int col = ct * 16 + lr;
            int cc = col - 64 + rloc;
            if (col < 129 && cc >= 0 && cc < 64)
                jwT[((size_t)b * 64 + cc) * 64 + rloc] = v[ct] * inv;
        }
        if (lr == 1) {
            float pv = acc[8][j] + b3v;
            p0[b * 64 + rloc] = 1.0f / (1.0f + expf(-pv));
        }
    }
}

// ---------------------------------------------------------------------------
// recur: MINIMAL kernel, one block = one batch, 64 threads (1 wave).
// Band column in 16 named f32x4 (tiny kernel, launch_bounds(64,1): nothing
// competes for VGPRs -> resident; signal: VGPR_Count >= 150).
// Per iter: asm DS broadcast cluster + 64 FMA + exponent-flush rescale
// (readfirstlane exponent, exact power-of-2, no cross-lane). Single butterfly
// reduce at loop exit: sum(log s_i) = log2(sum_c a_f) + sum E_i.
// ---------------------------------------------------------------------------
__global__ __launch_bounds__(64, 1) void recur_kernel(
    const float* __restrict__ jwT, const float* __restrict__ p0g,
    const float* __restrict__ em, const int* __restrict__ slen,
    float* __restrict__ out)
{
    __shared__ float em_s[128][65];
    __shared__ f32x4 a_bc4[16];
    const int b = blockIdx.x, c = threadIdx.x;

    const float* bb = jwT + ((size_t)b * 64 + c) * 64;
    f32x4 B0  = *(const f32x4*)(bb + 0);
    f32x4 B1  = *(const f32x4*)(bb + 4);
    f32x4 B2  = *(const f32x4*)(bb + 8);
    f32x4 B3  = *(const f32x4*)(bb + 12);
    f32x4 B4  = *(const f32x4*)(bb + 16);
    f32x4 B5  = *(const f32x4*)(bb + 20);
    f32x4 B6  = *(const f32x4*)(bb + 24);
    f32x4 B7  = *(const f32x4*)(bb + 28);
    f32x4 B8  = *(const f32x4*)(bb + 32);
    f32x4 B9  = *(const f32x4*)(bb + 36);
    f32x4 B10 = *(const f32x4*)(bb + 40);
    f32x4 B11 = *(const f32x4*)(bb + 44);
    f32x4 B12 = *(const f32x4*)(bb + 48);
    f32x4 B13 = *(const f32x4*)(bb + 52);
    f32x4 B14 = *(const f32x4*)(bb + 56);
    f32x4 B15 = *(const f32x4*)(bb + 60);

    {
        const float4* eg = (const float4*)(em + (size_t)b * 8192);
        #pragma unroll 8
        for (int q = 0; q < 32; ++q) {
            int i4 = c + q * 64;
            float4 v = eg[i4];
            int base = i4 * 4; int n = base >> 6; int ii = base & 63;
            em_s[n][ii] = v.x; em_s[n][ii + 1] = v.y; em_s[n][ii + 2] = v.z; em_s[n][ii + 3] = v.w;
        }
    }
    const float p0r = p0g[b * 64 + c];
    const int idx = slen[b] - 1;
    __syncthreads();

    float ut = em_s[c][0] + em_s[c + 64][0];   // a^_0
    int Eacc = 0;

    unsigned rbase = (unsigned)(uintptr_t)(__attribute__((address_space(3))) void*)&a_bc4[0];
    unsigned waddr = rbase + (unsigned)c * 4u;

    #pragma unroll 1
    for (int i = 1; i <= idx; ++i) {
        float aloc = ut;
        f32x4 A0,A1,A2,A3,A4,A5,A6,A7,A8,A9,A10,A11,A12,A13,A14,A15;
        asm volatile(
            "ds_write_b32 %17, %16\n\t"
            "s_waitcnt lgkmcnt(0)\n\t"
            "ds_read_b128 %0, %18 offset:0\n\t"
            "ds_read_b128 %1, %18 offset:16\n\t"
            "ds_read_b128 %2, %18 offset:32\n\t"
            "ds_read_b128 %3, %18 offset:48\n\t"
            "ds_read_b128 %4, %18 offset:64\n\t"
            "ds_read_b128 %5, %18 offset:80\n\t"
            "ds_read_b128 %6, %18 offset:96\n\t"
            "ds_read_b128 %7, %18 offset:112\n\t"
            "ds_read_b128 %8, %18 offset:128\n\t"
            "ds_read_b128 %9, %18 offset:144\n\t"
            "ds_read_b128 %10, %18 offset:160\n\t"
            "ds_read_b128 %11, %18 offset:176\n\t"
            "ds_read_b128 %12, %18 offset:192\n\t"
            "ds_read_b128 %13, %18 offset:208\n\t"
            "ds_read_b128 %14, %18 offset:224\n\t"
            "ds_read_b128 %15, %18 offset:240\n\t"
            "s_waitcnt lgkmcnt(0)"
            : "=&v"(A0), "=&v"(A1), "=&v"(A2),  "=&v"(A3),
              "=&v"(A4), "=&v"(A5), "=&v"(A6),  "=&v"(A7),
              "=&v"(A8), "=&v"(A9), "=&v"(A10), "=&v"(A11),
              "=&v"(A12),"=&v"(A13),"=&v"(A14), "=&v"(A15)
            : "v"(ut), "v"(waddr), "v"(rbase)
            : "memory");
        float s0 = 0.f, s1 = 0.f, s2 = 0.f, s3 = 0.f;
#define ACC4(AV, BV) do { \
        s0 = fmaf((AV)[0], (BV)[0], s0); \
        s1 = fmaf((AV)[1], (BV)[1], s1); \
        s2 = fmaf((AV)[2], (BV)[2], s2); \
        s3 = fmaf((AV)[3], (BV)[3], s3); \
} while (0)
        ACC4(A0, B0);   ACC4(A1, B1);   ACC4(A2, B2);   ACC4(A3, B3);
        ACC4(A4, B4);   ACC4(A5, B5);   ACC4(A6, B6);   ACC4(A7, B7);
        ACC4(A8, B8);   ACC4(A9, B9);   ACC4(A10, B10); ACC4(A11, B11);
        ACC4(A12, B12); ACC4(A13, B13); ACC4(A14, B14); ACC4(A15, B15);
#undef ACC4
        ut = ((s0 + s1) + (s2 + s3)) * em_s[c][i] + aloc * p0r * em_s[c + 64][i];
        // exponent-flush: uniform exact power-of-2 rescale, no reduce
        int bits = __builtin_amdgcn_readfirstlane(__float_as_int(ut));
        int ef = (bits >> 23) & 255;            // biased exponent of lane 0
        Eacc += ef - 127;
        ut *= __int_as_float((254 - ef) << 23); // * 2^(127-ef) exactly
    }
    // single final reduce: sum_c a^_f
    float r = ut;
    #pragma unroll
    for (int o = 1; o < 64; o <<= 1) r += __shfl_xor(r, o);
    if (c == 0) {
        float res = 1.0f;
        if (idx > 0)
            res = 1.0f + 0.6931471805599453f * ((float)Eacc + __log2f(r) + 7.0f * (float)idx);
        out[b] = res;
    }
}

extern "C" void kernel_launch(void* const* d_in, const int* in_sizes, int n_in,
                              void* d_out, int out_size, void* d_ws, size_t ws_size,
                              hipStream_t stream)
{
    const float* Y   = (const float*)d_in[0];
    const float* em  = (const float*)d_in[1];
    const int*   sl  = (const int*)d_in[2];
    const float* W1  = (const float*)d_in[3];
    const float* b1  = (const float*)d_in[4];
    const float* W2  = (const float*)d_in[5];
    const float* b2  = (const float*)d_in[6];
    const float* W3  = (const float*)d_in[7];
    const float* b3  = (const float*)d_in[8];
    float* out = (float*)d_out;
    char* ws = (char*)d_ws;

    __bf16* W1B  = (__bf16*)(ws + OFF_W1B);
    __bf16* W23B = (__bf16*)(ws + OFF_W23B);
    u16*    ts   = (u16*)(ws + OFF_TS);
    float*  jwT  = (float*)(ws + OFF_JWT);
    float*  p0   = (float*)(ws + OFF_P0);

    prep_kernel<<<292, 256, 0, stream>>>(W1, W2, W3, W1B, W23B);
    dim3 g1(128, 4);
    gemm1_kernel<<<g1, 256, 0, stream>>>(Y, (const u16*)W1B, b1, ts);
    band_kernel<<<128, 256, 0, stream>>>(ts, (const u16*)W23B, b2, b3, jwT, p0);
    recur_kernel<<<128, 64, 0, stream>>>(jwT, p0, em, sl, out);
}

// Round 10
// 85.074 us; speedup vs baseline: 1.2296x; 1.2296x over previous
//
#include <hip/hip_runtime.h>
#include <hip/hip_bf16.h>

typedef float f32x4 __attribute__((ext_vector_type(4)));
typedef __bf16 bf16x8 __attribute__((ext_vector_type(8)));
typedef unsigned short u16;

// Problem dims (fixed): B=128, T=64, H=1024, Hu=512, J=129, N=128, I=64, MJW=64
// ws layout
#define OFF_W1T  0u            // 512x1024 bf16 = 1048576 B  (W1T[n][k] = W1[k][n])
#define OFF_W23B 1048576u      // 144x512 bf16 fragment-order = 147456 B
#define OFF_TS   1196032u      // 8192x512 bf16 = 8388608 B
#define OFF_JWT  9584640u      // 128 x 64(col) x 64(row) f32 = 2097152 B
#define OFF_P0   11681792u     // 8192 f32 = 32768 B

static __device__ __forceinline__ u16 f2bf(float x) {
    __bf16 h = (__bf16)x;
    return __builtin_bit_cast(u16, h);
}

__device__ __forceinline__ void gload16(const void* g, void* l) {
    __builtin_amdgcn_global_load_lds(
        (const __attribute__((address_space(1))) void*)g,
        (__attribute__((address_space(3))) void*)l,
        16, 0, 0);
}

// ---------------------------------------------------------------------------
// prep: blocks 0..127 = coalesced LDS-tile transpose W1(1024x512 f32)->W1T bf16
//       blocks 128..163 = W2/W3 -> W23B in MFMA fragment order
// (round-6 version, known-good)
// ---------------------------------------------------------------------------
__global__ __launch_bounds__(256) void prep_kernel(
    const float* __restrict__ W1, const float* __restrict__ W2,
    const float* __restrict__ W3,
    __bf16* __restrict__ W1T, __bf16* __restrict__ W23B)
{
    const int t = threadIdx.x;
    if (blockIdx.x < 128) {
        __shared__ __bf16 lds_t[64][72];
        const int kt = blockIdx.x >> 3, nt = blockIdx.x & 7;
        const int k0 = kt * 64, n0 = nt * 64;
        {
            const int kr = t >> 2, c0 = (t & 3) * 16;
            const float* src = W1 + (size_t)(k0 + kr) * 512 + n0 + c0;
            #pragma unroll
            for (int q = 0; q < 4; ++q) {
                float4 v = *(const float4*)(src + q * 4);
                lds_t[kr][c0 + q * 4 + 0] = (__bf16)v.x;
                lds_t[kr][c0 + q * 4 + 1] = (__bf16)v.y;
                lds_t[kr][c0 + q * 4 + 2] = (__bf16)v.z;
                lds_t[kr][c0 + q * 4 + 3] = (__bf16)v.w;
            }
        }
        __syncthreads();
        {
            const int nr = t >> 2, kc = (t & 3) * 16;
            bf16x8 o0, o1;
            #pragma unroll
            for (int j = 0; j < 8; ++j) o0[j] = lds_t[kc + j][nr];
            #pragma unroll
            for (int j = 0; j < 8; ++j) o1[j] = lds_t[kc + 8 + j][nr];
            __bf16* dst = W1T + (size_t)(n0 + nr) * 1024 + k0 + kc;
            *(bf16x8*)(dst)     = o0;
            *(bf16x8*)(dst + 8) = o1;
        }
    } else {
        int g = (blockIdx.x - 128) * 256 + t;   // 0..9215
        if (g < 9216) {
            int n = g >> 6;            // 0..143
            int k8 = (g & 63) * 8;     // 0,8,..,504
            bf16x8 v;
            #pragma unroll
            for (int j = 0; j < 8; ++j) {
                int k = k8 + j;
                float x = 0.0f;
                if (n < 129) x = W2[(size_t)k * 129 + n];
                else if (n == 129) x = W3[k];
                v[j] = (__bf16)x;
            }
            int kk = k8 >> 5, lg = (k8 >> 3) & 3, ct = n >> 4, lr = n & 15;
            *(bf16x8*)&W23B[(((size_t)(kk * 9 + ct)) * 64 + lg * 16 + lr) * 8] = v;
        }
    }
}

// ---------------------------------------------------------------------------
// GEMM1 (round-6/7/8 version, best measured ~28us): global_load_lds 3-ring,
// counted vmcnt(8), raw barriers, T21 both-sides swizzle, tile 64x128 BK=32.
// ---------------------------------------------------------------------------
__global__ __launch_bounds__(256, 2) void gemm1_kernel(
    const float* __restrict__ Y, const __bf16* __restrict__ W1T,
    const float* __restrict__ b1, u16* __restrict__ ts)
{
    __shared__ float  As[3][64 * 32];    // f32 [64 rows][32 k], 8KB/buf
    __shared__ __bf16 Bs[3][128 * 32];   // bf16 [128 rows][32 k], 8KB/buf
    const int tid = threadIdx.x;
    const int m0 = blockIdx.x * 64, n0 = blockIdx.y * 128;
    const int wid = tid >> 6, lane = tid & 63;
    const int wr = wid >> 1, wc = wid & 1;
    const int lr = lane & 15, lg = lane >> 4;

    const int al = lane >> 3;            // A sub-row within KB (also row&7)
    const int au = (lane & 7) ^ al;      // A data unit
    const float* yA0 = Y + (size_t)(m0 + (wid * 2 + 0) * 8 + al) * 1024 + au * 4;
    const float* yA1 = Y + (size_t)(m0 + (wid * 2 + 1) * 8 + al) * 1024 + au * 4;
    const int bl = lane >> 2;            // B sub-row within KB
    const int bu = (lane & 3) ^ (bl & 3);
    const __bf16* wB0 = W1T + (size_t)(n0 + (wid * 2 + 0) * 16 + bl) * 1024 + bu * 8;
    const __bf16* wB1 = W1T + (size_t)(n0 + (wid * 2 + 1) * 16 + bl) * 1024 + bu * 8;

    f32x4 acc[2][4];
    #pragma unroll
    for (int m = 0; m < 2; m++)
        #pragma unroll
        for (int n = 0; n < 4; n++) { f32x4 z = {0.f,0.f,0.f,0.f}; acc[m][n] = z; }

#define STAGE(buf, kt) do { \
    gload16(yA0 + (kt) * 32, &As[buf][(wid * 2 + 0) * 256]); \
    gload16(yA1 + (kt) * 32, &As[buf][(wid * 2 + 1) * 256]); \
    gload16(wB0 + (kt) * 32, &Bs[buf][(wid * 2 + 0) * 512]); \
    gload16(wB1 + (kt) * 32, &Bs[buf][(wid * 2 + 1) * 512]); \
} while (0)

#define COMPUTE(buf) do { \
    bf16x8 af[2]; bf16x8 bfr[4]; \
    _Pragma("unroll") \
    for (int m = 0; m < 2; ++m) { \
        const int row = wr * 32 + m * 16 + lr; \
        const int r7 = row & 7; \
        float4 h0 = *(const float4*)&As[buf][row * 32 + (((lg * 2 + 0) ^ r7) * 4)]; \
        float4 h1 = *(const float4*)&As[buf][row * 32 + (((lg * 2 + 1) ^ r7) * 4)]; \
        bf16x8 tt; \
        tt[0]=(__bf16)h0.x; tt[1]=(__bf16)h0.y; tt[2]=(__bf16)h0.z; tt[3]=(__bf16)h0.w; \
        tt[4]=(__bf16)h1.x; tt[5]=(__bf16)h1.y; tt[6]=(__bf16)h1.z; tt[7]=(__bf16)h1.w; \
        af[m] = tt; \
    } \
    _Pragma("unroll") \
    for (int n = 0; n < 4; ++n) { \
        const int rowb = wc * 64 + n * 16 + lr; \
        bfr[n] = *(const bf16x8*)&Bs[buf][rowb * 32 + ((lg ^ (rowb & 3)) * 8)]; \
    } \
    __builtin_amdgcn_s_setprio(1); \
    _Pragma("unroll") \
    for (int m = 0; m < 2; ++m) \
        _Pragma("unroll") \
        for (int n = 0; n < 4; ++n) \
            acc[m][n] = __builtin_amdgcn_mfma_f32_16x16x32_bf16(af[m], bfr[n], acc[m][n], 0, 0, 0); \
    __builtin_amdgcn_s_setprio(0); \
} while (0)

#define KSTEP(buf, kt, VM, DO_STAGE) do { \
    asm volatile("s_waitcnt vmcnt(" #VM ")" ::: "memory"); \
    __builtin_amdgcn_s_barrier(); \
    COMPUTE(buf); \
    asm volatile("s_waitcnt lgkmcnt(0)" ::: "memory"); \
    __builtin_amdgcn_s_barrier(); \
    if (DO_STAGE) STAGE(buf, (kt) + 3); \
} while (0)

    STAGE(0, 0); STAGE(1, 1); STAGE(2, 2);
    #pragma unroll 1
    for (int base = 0; base < 27; base += 3) {
        KSTEP(0, base + 0, 8, 1);
        KSTEP(1, base + 1, 8, 1);
        KSTEP(2, base + 2, 8, 1);
    }
    KSTEP(0, 27, 8, 1);
    KSTEP(1, 28, 8, 1);
    KSTEP(2, 29, 8, 0);
    KSTEP(0, 30, 4, 0);
    KSTEP(1, 31, 0, 0);

    // epilogue: bias + tanh + bf16 store
    #pragma unroll
    for (int m = 0; m < 2; m++) {
        #pragma unroll
        for (int n = 0; n < 4; n++) {
            int col = n0 + wc * 64 + n * 16 + lr;
            float bias = b1[col];
            #pragma unroll
            for (int j = 0; j < 4; j++) {
                int row = m0 + wr * 32 + m * 16 + lg * 4 + j;
                float v = tanhf(acc[m][n][j] + bias);
                ts[(size_t)row * 512 + col] = f2bf(v);
            }
        }
    }
#undef STAGE
#undef COMPUTE
#undef KSTEP
}

// ---------------------------------------------------------------------------
// band: GEMM2 + softmax + sigmoid only. One block = one batch (4 waves).
// Writes pre-shifted TRANSPOSED band jwT[b][c][k] = M_b[k][c] and p0.
// ---------------------------------------------------------------------------
__global__ __launch_bounds__(256) void band_kernel(
    const u16* __restrict__ ts, const u16* __restrict__ W23B,
    const float* __restrict__ b2, const float* __restrict__ b3,
    float* __restrict__ jwT, float* __restrict__ p0)
{
    const int b = blockIdx.x;
    const int tid = threadIdx.x;
    const int w = tid >> 6, lane = tid & 63;
    const int lr = lane & 15, lg = lane >> 4;
    const int r0 = b * 64 + w * 16;

    f32x4 acc[9];
    #pragma unroll
    for (int ct = 0; ct < 9; ct++) { f32x4 z = {0.f,0.f,0.f,0.f}; acc[ct] = z; }

    #pragma unroll 4
    for (int kk = 0; kk < 16; ++kk) {
        bf16x8 a = *(const bf16x8*)(ts + (size_t)(r0 + lr) * 512 + kk * 32 + lg * 8);
        #pragma unroll
        for (int ct = 0; ct < 9; ct++) {
            bf16x8 bv = *(const bf16x8*)(W23B + ((size_t)(kk * 9 + ct) * 64 + lane) * 8);
            acc[ct] = __builtin_amdgcn_mfma_f32_16x16x32_bf16(a, bv, acc[ct], 0, 0, 0);
        }
    }

    float b3v = b3[0];
    #pragma unroll
    for (int j = 0; j < 4; j++) {
        int rloc = w * 16 + lg * 4 + j;   // row within batch (0..63)
        float v[9];
        float mx = -1e30f;
        #pragma unroll
        for (int ct = 0; ct < 9; ct++) {
            int col = ct * 16 + lr;
            if (col < 129) { float x = acc[ct][j] + b2[col]; v[ct] = x; mx = fmaxf(mx, x); }
            else v[ct] = -1e30f;
        }
        #pragma unroll
        for (int o = 1; o < 16; o <<= 1) mx = fmaxf(mx, __shfl_xor(mx, o));
        float sum = 0.f;
        #pragma unroll
        for (int ct = 0; ct < 9; ct++) {
            int col = ct * 16 + lr;
            if (col < 129) { float e = expf(v[ct] - mx); v[ct] = e; sum += e; }
        }
        #pragma unroll
        for (int o = 1; o < 16; o <<= 1) sum += __shfl_xor(sum, o);
        float inv = 1.0f / sum;
        #pragma unroll
        for (int ct = 0; ct < 9; ct++) {
            int col = ct * 16 + lr;
            int cc = col - 64 + rloc;
            if (col < 129 && cc >= 0 && cc < 64)
                jwT[((size_t)b * 64 + cc) * 64 + rloc] = v[ct] * inv;
        }
        if (lr == 1) {
            float pv = acc[8][j] + b3v;
            p0[b * 64 + rloc] = 1.0f / (1.0f + expf(-pv));
        }
    }
}

// ---------------------------------------------------------------------------
// recur: MINIMAL kernel, one block = one batch, 64 threads (1 wave).
// asm DS broadcast cluster + 64 FMA + exponent-flush rescale; one reduce at
// loop exit. (round-9 version, passed absmax 0)
// ---------------------------------------------------------------------------
__global__ __launch_bounds__(64, 1) void recur_kernel(
    const float* __restrict__ jwT, const float* __restrict__ p0g,
    const float* __restrict__ em, const int* __restrict__ slen,
    float* __restrict__ out)
{
    __shared__ float em_s[128][65];
    __shared__ f32x4 a_bc4[16];
    const int b = blockIdx.x, c = threadIdx.x;

    const float* bb = jwT + ((size_t)b * 64 + c) * 64;
    f32x4 B0  = *(const f32x4*)(bb + 0);
    f32x4 B1  = *(const f32x4*)(bb + 4);
    f32x4 B2  = *(const f32x4*)(bb + 8);
    f32x4 B3  = *(const f32x4*)(bb + 12);
    f32x4 B4  = *(const f32x4*)(bb + 16);
    f32x4 B5  = *(const f32x4*)(bb + 20);
    f32x4 B6  = *(const f32x4*)(bb + 24);
    f32x4 B7  = *(const f32x4*)(bb + 28);
    f32x4 B8  = *(const f32x4*)(bb + 32);
    f32x4 B9  = *(const f32x4*)(bb + 36);
    f32x4 B10 = *(const f32x4*)(bb + 40);
    f32x4 B11 = *(const f32x4*)(bb + 44);
    f32x4 B12 = *(const f32x4*)(bb + 48);
    f32x4 B13 = *(const f32x4*)(bb + 52);
    f32x4 B14 = *(const f32x4*)(bb + 56);
    f32x4 B15 = *(const f32x4*)(bb + 60);

    {
        const float4* eg = (const float4*)(em + (size_t)b * 8192);
        #pragma unroll 8
        for (int q = 0; q < 32; ++q) {
            int i4 = c + q * 64;
            float4 v = eg[i4];
            int base = i4 * 4; int n = base >> 6; int ii = base & 63;
            em_s[n][ii] = v.x; em_s[n][ii + 1] = v.y; em_s[n][ii + 2] = v.z; em_s[n][ii + 3] = v.w;
        }
    }
    const float p0r = p0g[b * 64 + c];
    const int idx = slen[b] - 1;
    __syncthreads();

    float ut = em_s[c][0] + em_s[c + 64][0];   // a^_0
    int Eacc = 0;

    unsigned rbase = (unsigned)(uintptr_t)(__attribute__((address_space(3))) void*)&a_bc4[0];
    unsigned waddr = rbase + (unsigned)c * 4u;

    #pragma unroll 1
    for (int i = 1; i <= idx; ++i) {
        float aloc = ut;
        f32x4 A0,A1,A2,A3,A4,A5,A6,A7,A8,A9,A10,A11,A12,A13,A14,A15;
        asm volatile(
            "ds_write_b32 %17, %16\n\t"
            "s_waitcnt lgkmcnt(0)\n\t"
            "ds_read_b128 %0, %18 offset:0\n\t"
            "ds_read_b128 %1, %18 offset:16\n\t"
            "ds_read_b128 %2, %18 offset:32\n\t"
            "ds_read_b128 %3, %18 offset:48\n\t"
            "ds_read_b128 %4, %18 offset:64\n\t"
            "ds_read_b128 %5, %18 offset:80\n\t"
            "ds_read_b128 %6, %18 offset:96\n\t"
            "ds_read_b128 %7, %18 offset:112\n\t"
            "ds_read_b128 %8, %18 offset:128\n\t"
            "ds_read_b128 %9, %18 offset:144\n\t"
            "ds_read_b128 %10, %18 offset:160\n\t"
            "ds_read_b128 %11, %18 offset:176\n\t"
            "ds_read_b128 %12, %18 offset:192\n\t"
            "ds_read_b128 %13, %18 offset:208\n\t"
            "ds_read_b128 %14, %18 offset:224\n\t"
            "ds_read_b128 %15, %18 offset:240\n\t"
            "s_waitcnt lgkmcnt(0)"
            : "=&v"(A0), "=&v"(A1), "=&v"(A2),  "=&v"(A3),
              "=&v"(A4), "=&v"(A5), "=&v"(A6),  "=&v"(A7),
              "=&v"(A8), "=&v"(A9), "=&v"(A10), "=&v"(A11),
              "=&v"(A12),"=&v"(A13),"=&v"(A14), "=&v"(A15)
            : "v"(ut), "v"(waddr), "v"(rbase)
            : "memory");
        float s0 = 0.f, s1 = 0.f, s2 = 0.f, s3 = 0.f;
#define ACC4(AV, BV) do { \
        s0 = fmaf((AV)[0], (BV)[0], s0); \
        s1 = fmaf((AV)[1], (BV)[1], s1); \
        s2 = fmaf((AV)[2], (BV)[2], s2); \
        s3 = fmaf((AV)[3], (BV)[3], s3); \
} while (0)
        ACC4(A0, B0);   ACC4(A1, B1);   ACC4(A2, B2);   ACC4(A3, B3);
        ACC4(A4, B4);   ACC4(A5, B5);   ACC4(A6, B6);   ACC4(A7, B7);
        ACC4(A8, B8);   ACC4(A9, B9);   ACC4(A10, B10); ACC4(A11, B11);
        ACC4(A12, B12); ACC4(A13, B13); ACC4(A14, B14); ACC4(A15, B15);
#undef ACC4
        ut = ((s0 + s1) + (s2 + s3)) * em_s[c][i] + aloc * p0r * em_s[c + 64][i];
        // exponent-flush: uniform exact power-of-2 rescale, no reduce
        int bits = __builtin_amdgcn_readfirstlane(__float_as_int(ut));
        int ef = (bits >> 23) & 255;            // biased exponent of lane 0
        Eacc += ef - 127;
        ut *= __int_as_float((254 - ef) << 23); // * 2^(127-ef) exactly
    }
    // single final reduce: sum_c a^_f
    float r = ut;
    #pragma unroll
    for (int o = 1; o < 64; o <<= 1) r += __shfl_xor(r, o);
    if (c == 0) {
        float res = 1.0f;
        if (idx > 0)
            res = 1.0f + 0.6931471805599453f * ((float)Eacc + __log2f(r) + 7.0f * (float)idx);
        out[b] = res;
    }
}

extern "C" void kernel_launch(void* const* d_in, const int* in_sizes, int n_in,
                              void* d_out, int out_size, void* d_ws, size_t ws_size,
                              hipStream_t stream)
{
    const float* Y   = (const float*)d_in[0];
    const float* em  = (const float*)d_in[1];
    const int*   sl  = (const int*)d_in[2];
    const float* W1  = (const float*)d_in[3];
    const float* b1  = (const float*)d_in[4];
    const float* W2  = (const float*)d_in[5];
    const float* b2  = (const float*)d_in[6];
    const float* W3  = (const float*)d_in[7];
    const float* b3  = (const float*)d_in[8];
    float* out = (float*)d_out;
    char* ws = (char*)d_ws;

    __bf16* W1T  = (__bf16*)(ws + OFF_W1T);
    __bf16* W23B = (__bf16*)(ws + OFF_W23B);
    u16*    ts   = (u16*)(ws + OFF_TS);
    float*  jwT  = (float*)(ws + OFF_JWT);
    float*  p0   = (float*)(ws + OFF_P0);

    prep_kernel<<<164, 256, 0, stream>>>(W1, W2, W3, W1T, W23B);
    dim3 g1(128, 4);
    gemm1_kernel<<<g1, 256, 0, stream>>>(Y, W1T, b1, ts);
    band_kernel<<<128, 256, 0, stream>>>(ts, (const u16*)W23B, b2, b3, jwT, p0);
    recur_kernel<<<128, 64, 0, stream>>>(jwT, p0, em, sl, out);
}

// Round 11
// 79.983 us; speedup vs baseline: 1.3079x; 1.0637x over previous
//
#include <hip/hip_runtime.h>
#include <hip/hip_bf16.h>

typedef float f32x4 __attribute__((ext_vector_type(4)));
typedef __bf16 bf16x8 __attribute__((ext_vector_type(8)));
typedef unsigned short u16;

// Problem dims (fixed): B=128, T=64, H=1024, Hu=512, J=129, N=128, I=64, MJW=64
// ws layout
#define OFF_W1T  0u            // 512x1024 bf16 = 1048576 B  (W1T[n][k] = W1[k][n])
#define OFF_W23B 1048576u      // 144x512 bf16 fragment-order = 147456 B
#define OFF_TS   1196032u      // 8192x512 bf16 = 8388608 B
#define OFF_JWT  9584640u      // 128 x 64(col) x 64(row) f32 = 2097152 B
#define OFF_P0   11681792u     // 8192 f32 = 32768 B

static __device__ __forceinline__ u16 f2bf(float x) {
    __bf16 h = (__bf16)x;
    return __builtin_bit_cast(u16, h);
}

__device__ __forceinline__ void gload16(const void* g, void* l) {
    __builtin_amdgcn_global_load_lds(
        (const __attribute__((address_space(1))) void*)g,
        (__attribute__((address_space(3))) void*)l,
        16, 0, 0);
}

// ---------------------------------------------------------------------------
// prep: blocks 0..127 = coalesced LDS-tile transpose W1(1024x512 f32)->W1T bf16
//       blocks 128..163 = W2/W3 -> W23B in MFMA fragment order
// ---------------------------------------------------------------------------
__global__ __launch_bounds__(256) void prep_kernel(
    const float* __restrict__ W1, const float* __restrict__ W2,
    const float* __restrict__ W3,
    __bf16* __restrict__ W1T, __bf16* __restrict__ W23B)
{
    const int t = threadIdx.x;
    if (blockIdx.x < 128) {
        __shared__ __bf16 lds_t[64][72];
        const int kt = blockIdx.x >> 3, nt = blockIdx.x & 7;
        const int k0 = kt * 64, n0 = nt * 64;
        {
            const int kr = t >> 2, c0 = (t & 3) * 16;
            const float* src = W1 + (size_t)(k0 + kr) * 512 + n0 + c0;
            #pragma unroll
            for (int q = 0; q < 4; ++q) {
                float4 v = *(const float4*)(src + q * 4);
                lds_t[kr][c0 + q * 4 + 0] = (__bf16)v.x;
                lds_t[kr][c0 + q * 4 + 1] = (__bf16)v.y;
                lds_t[kr][c0 + q * 4 + 2] = (__bf16)v.z;
                lds_t[kr][c0 + q * 4 + 3] = (__bf16)v.w;
            }
        }
        __syncthreads();
        {
            const int nr = t >> 2, kc = (t & 3) * 16;
            bf16x8 o0, o1;
            #pragma unroll
            for (int j = 0; j < 8; ++j) o0[j] = lds_t[kc + j][nr];
            #pragma unroll
            for (int j = 0; j < 8; ++j) o1[j] = lds_t[kc + 8 + j][nr];
            __bf16* dst = W1T + (size_t)(n0 + nr) * 1024 + k0 + kc;
            *(bf16x8*)(dst)     = o0;
            *(bf16x8*)(dst + 8) = o1;
        }
    } else {
        int g = (blockIdx.x - 128) * 256 + t;   // 0..9215
        if (g < 9216) {
            int n = g >> 6;            // 0..143
            int k8 = (g & 63) * 8;     // 0,8,..,504
            bf16x8 v;
            #pragma unroll
            for (int j = 0; j < 8; ++j) {
                int k = k8 + j;
                float x = 0.0f;
                if (n < 129) x = W2[(size_t)k * 129 + n];
                else if (n == 129) x = W3[k];
                v[j] = (__bf16)x;
            }
            int kk = k8 >> 5, lg = (k8 >> 3) & 3, ct = n >> 4, lr = n & 15;
            *(bf16x8*)&W23B[(((size_t)(kk * 9 + ct)) * 64 + lg * 16 + lr) * 8] = v;
        }
    }
}

// ---------------------------------------------------------------------------
// GEMM1: ring-4 LDS, stage distance 3, ONE barrier per K-step, counted
// vmcnt(8). B swizzle keyed on (row>>1)&3 (64B rows alias banks in pairs).
// Tile 64x128, BK=32, 4 waves (2x2), wave tile 32x64.
// ---------------------------------------------------------------------------
__global__ __launch_bounds__(256, 2) void gemm1_kernel(
    const float* __restrict__ Y, const __bf16* __restrict__ W1T,
    const float* __restrict__ b1, u16* __restrict__ ts)
{
    __shared__ float  As[4][64 * 32];    // f32, 8KB/buf
    __shared__ __bf16 Bs[4][128 * 32];   // bf16, 8KB/buf
    const int tid = threadIdx.x;
    const int m0 = blockIdx.x * 64, n0 = blockIdx.y * 128;
    const int wid = tid >> 6, lane = tid & 63;
    const int wr = wid >> 1, wc = wid & 1;
    const int lr = lane & 15, lg = lane >> 4;

    const int al = lane >> 3;            // A sub-row (row&7)
    const int au = (lane & 7) ^ al;      // A data unit (pre-swizzled source)
    const float* yA0 = Y + (size_t)(m0 + (wid * 2 + 0) * 8 + al) * 1024 + au * 4;
    const float* yA1 = Y + (size_t)(m0 + (wid * 2 + 1) * 8 + al) * 1024 + au * 4;
    const int bl = lane >> 2;            // B sub-row within 16-row chunk
    const int bu = (lane & 3) ^ ((bl >> 1) & 3);   // keyed on (row>>1)&3
    const __bf16* wB0 = W1T + (size_t)(n0 + (wid * 2 + 0) * 16 + bl) * 1024 + bu * 8;
    const __bf16* wB1 = W1T + (size_t)(n0 + (wid * 2 + 1) * 16 + bl) * 1024 + bu * 8;

    f32x4 acc[2][4];
    #pragma unroll
    for (int m = 0; m < 2; m++)
        #pragma unroll
        for (int n = 0; n < 4; n++) { f32x4 z = {0.f,0.f,0.f,0.f}; acc[m][n] = z; }

#define STAGE(buf, kt) do { \
    gload16(yA0 + (kt) * 32, &As[buf][(wid * 2 + 0) * 256]); \
    gload16(yA1 + (kt) * 32, &As[buf][(wid * 2 + 1) * 256]); \
    gload16(wB0 + (kt) * 32, &Bs[buf][(wid * 2 + 0) * 512]); \
    gload16(wB1 + (kt) * 32, &Bs[buf][(wid * 2 + 1) * 512]); \
} while (0)

#define COMPUTE(buf) do { \
    bf16x8 af[2]; bf16x8 bfr[4]; \
    _Pragma("unroll") \
    for (int m = 0; m < 2; ++m) { \
        const int row = wr * 32 + m * 16 + lr; \
        const int r7 = row & 7; \
        float4 h0 = *(const float4*)&As[buf][row * 32 + (((lg * 2 + 0) ^ r7) * 4)]; \
        float4 h1 = *(const float4*)&As[buf][row * 32 + (((lg * 2 + 1) ^ r7) * 4)]; \
        bf16x8 tt; \
        tt[0]=(__bf16)h0.x; tt[1]=(__bf16)h0.y; tt[2]=(__bf16)h0.z; tt[3]=(__bf16)h0.w; \
        tt[4]=(__bf16)h1.x; tt[5]=(__bf16)h1.y; tt[6]=(__bf16)h1.z; tt[7]=(__bf16)h1.w; \
        af[m] = tt; \
    } \
    _Pragma("unroll") \
    for (int n = 0; n < 4; ++n) { \
        const int rowb = wc * 64 + n * 16 + lr; \
        bfr[n] = *(const bf16x8*)&Bs[buf][rowb * 32 + ((lg ^ ((rowb >> 1) & 3)) * 8)]; \
    } \
    __builtin_amdgcn_s_setprio(1); \
    _Pragma("unroll") \
    for (int m = 0; m < 2; ++m) \
        _Pragma("unroll") \
        for (int n = 0; n < 4; ++n) \
            acc[m][n] = __builtin_amdgcn_mfma_f32_16x16x32_bf16(af[m], bfr[n], acc[m][n], 0, 0, 0); \
    __builtin_amdgcn_s_setprio(0); \
} while (0)

// one barrier per step: buffer staged here was last read one barrier ago;
// per-wave vmcnt(VM) BEFORE the barrier => all waves' loads for this buf landed
#define KSTEP(buf, kt, VM, DO_STAGE) do { \
    asm volatile("s_waitcnt vmcnt(" #VM ")" ::: "memory"); \
    __builtin_amdgcn_s_barrier(); \
    COMPUTE(buf); \
    if (DO_STAGE) STAGE(((kt) + 3) & 3, (kt) + 3); \
} while (0)

    STAGE(0, 0); STAGE(1, 1); STAGE(2, 2);
    #pragma unroll 1
    for (int base = 0; base < 28; base += 4) {
        KSTEP(0, base + 0, 8, 1);
        KSTEP(1, base + 1, 8, 1);
        KSTEP(2, base + 2, 8, 1);
        KSTEP(3, base + 3, 8, 1);
    }
    KSTEP(0, 28, 8, 0);   // t=28 would stage kt=31 -- folded below
    STAGE(3, 31);
    KSTEP(1, 29, 8, 0);
    KSTEP(2, 30, 4, 0);
    KSTEP(3, 31, 0, 0);

    // epilogue: bias + tanh + bf16 store
    #pragma unroll
    for (int m = 0; m < 2; m++) {
        #pragma unroll
        for (int n = 0; n < 4; n++) {
            int col = n0 + wc * 64 + n * 16 + lr;
            float bias = b1[col];
            #pragma unroll
            for (int j = 0; j < 4; j++) {
                int row = m0 + wr * 32 + m * 16 + lg * 4 + j;
                float v = tanhf(acc[m][n][j] + bias);
                ts[(size_t)row * 512 + col] = f2bf(v);
            }
        }
    }
#undef STAGE
#undef COMPUTE
#undef KSTEP
}

// ---------------------------------------------------------------------------
// band: GEMM2 + softmax + sigmoid only. One block = one batch (4 waves).
// Writes pre-shifted TRANSPOSED band jwT[b][c][k] = M_b[k][c] and p0.
// ---------------------------------------------------------------------------
__global__ __launch_bounds__(256) void band_kernel(
    const u16* __restrict__ ts, const u16* __restrict__ W23B,
    const float* __restrict__ b2, const float* __restrict__ b3,
    float* __restrict__ jwT, float* __restrict__ p0)
{
    const int b = blockIdx.x;
    const int tid = threadIdx.x;
    const int w = tid >> 6, lane = tid & 63;
    const int lr = lane & 15, lg = lane >> 4;
    const int r0 = b * 64 + w * 16;

    f32x4 acc[9];
    #pragma unroll
    for (int ct = 0; ct < 9; ct++) { f32x4 z = {0.f,0.f,0.f,0.f}; acc[ct] = z; }

    #pragma unroll 4
    for (int kk = 0; kk < 16; ++kk) {
        bf16x8 a = *(const bf16x8*)(ts + (size_t)(r0 + lr) * 512 + kk * 32 + lg * 8);
        #pragma unroll
        for (int ct = 0; ct < 9; ct++) {
            bf16x8 bv = *(const bf16x8*)(W23B + ((size_t)(kk * 9 + ct) * 64 + lane) * 8);
            acc[ct] = __builtin_amdgcn_mfma_f32_16x16x32_bf16(a, bv, acc[ct], 0, 0, 0);
        }
    }

    float b3v = b3[0];
    #pragma unroll
    for (int j = 0; j < 4; j++) {
        int rloc = w * 16 + lg * 4 + j;   // row within batch (0..63)
        float v[9];
        float mx = -1e30f;
        #pragma unroll
        for (int ct = 0; ct < 9; ct++) {
            int col = ct * 16 + lr;
            if (col < 129) { float x = acc[ct][j] + b2[col]; v[ct] = x; mx = fmaxf(mx, x); }
            else v[ct] = -1e30f;
        }
        #pragma unroll
        for (int o = 1; o < 16; o <<= 1) mx = fmaxf(mx, __shfl_xor(mx, o));
        float sum = 0.f;
        #pragma unroll
        for (int ct = 0; ct < 9; ct++) {
            int col = ct * 16 + lr;
            if (col < 129) { float e = expf(v[ct] - mx); v[ct] = e; sum += e; }
        }
        #pragma unroll
        for (int o = 1; o < 16; o <<= 1) sum += __shfl_xor(sum, o);
        float inv = 1.0f / sum;
        #pragma unroll
        for (int ct = 0; ct < 9; ct++) {
            int col = ct * 16 + lr;
            int cc = col - 64 + rloc;
            if (col < 129 && cc >= 0 && cc < 64)
                jwT[((size_t)b * 64 + cc) * 64 + rloc] = v[ct] * inv;
        }
        if (lr == 1) {
            float pv = acc[8][j] + b3v;
            p0[b * 64 + rloc] = 1.0f / (1.0f + expf(-pv));
        }
    }
}

// ---------------------------------------------------------------------------
// recur: one block = one batch, 64 threads (1 wave).
// asm DS broadcast cluster WITHOUT mid-wait (same-wave DS ops execute in
// order: reads queue behind the write) + em prefetch into regs (DS latency
// hidden under FMA chain) + 8 accumulators. Exponent-flush rescale; one
// butterfly reduce at loop exit.
// ---------------------------------------------------------------------------
__global__ __launch_bounds__(64, 1) void recur_kernel(
    const float* __restrict__ jwT, const float* __restrict__ p0g,
    const float* __restrict__ em, const int* __restrict__ slen,
    float* __restrict__ out)
{
    __shared__ float em_s[128][65];
    __shared__ f32x4 a_bc4[16];
    const int b = blockIdx.x, c = threadIdx.x;

    const float* bb = jwT + ((size_t)b * 64 + c) * 64;
    f32x4 B0  = *(const f32x4*)(bb + 0);
    f32x4 B1  = *(const f32x4*)(bb + 4);
    f32x4 B2  = *(const f32x4*)(bb + 8);
    f32x4 B3  = *(const f32x4*)(bb + 12);
    f32x4 B4  = *(const f32x4*)(bb + 16);
    f32x4 B5  = *(const f32x4*)(bb + 20);
    f32x4 B6  = *(const f32x4*)(bb + 24);
    f32x4 B7  = *(const f32x4*)(bb + 28);
    f32x4 B8  = *(const f32x4*)(bb + 32);
    f32x4 B9  = *(const f32x4*)(bb + 36);
    f32x4 B10 = *(const f32x4*)(bb + 40);
    f32x4 B11 = *(const f32x4*)(bb + 44);
    f32x4 B12 = *(const f32x4*)(bb + 48);
    f32x4 B13 = *(const f32x4*)(bb + 52);
    f32x4 B14 = *(const f32x4*)(bb + 56);
    f32x4 B15 = *(const f32x4*)(bb + 60);

    {
        const float4* eg = (const float4*)(em + (size_t)b * 8192);
        #pragma unroll 8
        for (int q = 0; q < 32; ++q) {
            int i4 = c + q * 64;
            float4 v = eg[i4];
            int base = i4 * 4; int n = base >> 6; int ii = base & 63;
            em_s[n][ii] = v.x; em_s[n][ii + 1] = v.y; em_s[n][ii + 2] = v.z; em_s[n][ii + 3] = v.w;
        }
    }
    const float p0r = p0g[b * 64 + c];
    const int idx = slen[b] - 1;
    __syncthreads();

    float ut = em_s[c][0] + em_s[c + 64][0];   // a^_0
    int Eacc = 0;

    unsigned rbase = (unsigned)(uintptr_t)(__attribute__((address_space(3))) void*)&a_bc4[0];
    unsigned waddr = rbase + (unsigned)c * 4u;

    float em_lo = em_s[c][1];       // prefetched for i=1
    float em_hi = em_s[c + 64][1];

    #pragma unroll 1
    for (int i = 1; i <= idx; ++i) {
        float aloc = ut;
        f32x4 A0,A1,A2,A3,A4,A5,A6,A7,A8,A9,A10,A11,A12,A13,A14,A15;
        asm volatile(
            "ds_write_b32 %17, %16\n\t"
            "ds_read_b128 %0, %18 offset:0\n\t"
            "ds_read_b128 %1, %18 offset:16\n\t"
            "ds_read_b128 %2, %18 offset:32\n\t"
            "ds_read_b128 %3, %18 offset:48\n\t"
            "ds_read_b128 %4, %18 offset:64\n\t"
            "ds_read_b128 %5, %18 offset:80\n\t"
            "ds_read_b128 %6, %18 offset:96\n\t"
            "ds_read_b128 %7, %18 offset:112\n\t"
            "ds_read_b128 %8, %18 offset:128\n\t"
            "ds_read_b128 %9, %18 offset:144\n\t"
            "ds_read_b128 %10, %18 offset:160\n\t"
            "ds_read_b128 %11, %18 offset:176\n\t"
            "ds_read_b128 %12, %18 offset:192\n\t"
            "ds_read_b128 %13, %18 offset:208\n\t"
            "ds_read_b128 %14, %18 offset:224\n\t"
            "ds_read_b128 %15, %18 offset:240\n\t"
            "s_waitcnt lgkmcnt(0)"
            : "=&v"(A0), "=&v"(A1), "=&v"(A2),  "=&v"(A3),
              "=&v"(A4), "=&v"(A5), "=&v"(A6),  "=&v"(A7),
              "=&v"(A8), "=&v"(A9), "=&v"(A10), "=&v"(A11),
              "=&v"(A12),"=&v"(A13),"=&v"(A14), "=&v"(A15)
            : "v"(ut), "v"(waddr), "v"(rbase)
            : "memory");
        // prefetch next-iter em (issued now, consumed next iter -> latency hidden)
        float nlo = em_s[c][i + 1];          // col 64 pad makes i+1=64 safe
        float nhi = em_s[c + 64][i + 1];
        float s0 = 0.f, s1 = 0.f, s2 = 0.f, s3 = 0.f;
        float s4 = 0.f, s5 = 0.f, s6 = 0.f, s7 = 0.f;
#define ACC8(AV, BV, CV, DV) do { \
        s0 = fmaf((AV)[0], (BV)[0], s0); \
        s1 = fmaf((AV)[1], (BV)[1], s1); \
        s2 = fmaf((AV)[2], (BV)[2], s2); \
        s3 = fmaf((AV)[3], (BV)[3], s3); \
        s4 = fmaf((CV)[0], (DV)[0], s4); \
        s5 = fmaf((CV)[1], (DV)[1], s5); \
        s6 = fmaf((CV)[2], (DV)[2], s6); \
        s7 = fmaf((CV)[3], (DV)[3], s7); \
} while (0)
        ACC8(A0, B0,  A1, B1);   ACC8(A2, B2,  A3, B3);
        ACC8(A4, B4,  A5, B5);   ACC8(A6, B6,  A7, B7);
        ACC8(A8, B8,  A9, B9);   ACC8(A10, B10, A11, B11);
        ACC8(A12, B12, A13, B13); ACC8(A14, B14, A15, B15);
#undef ACC8
        float sum = ((s0 + s1) + (s2 + s3)) + ((s4 + s5) + (s6 + s7));
        ut = sum * em_lo + aloc * p0r * em_hi;
        // exponent-flush: uniform exact power-of-2 rescale, no reduce
        int bits = __builtin_amdgcn_readfirstlane(__float_as_int(ut));
        int ef = (bits >> 23) & 255;
        Eacc += ef - 127;
        ut *= __int_as_float((254 - ef) << 23);
        em_lo = nlo; em_hi = nhi;
    }
    // single final reduce
    float r = ut;
    #pragma unroll
    for (int o = 1; o < 64; o <<= 1) r += __shfl_xor(r, o);
    if (c == 0) {
        float res = 1.0f;
        if (idx > 0)
            res = 1.0f + 0.6931471805599453f * ((float)Eacc + __log2f(r) + 7.0f * (float)idx);
        out[b] = res;
    }
}

extern "C" void kernel_launch(void* const* d_in, const int* in_sizes, int n_in,
                              void* d_out, int out_size, void* d_ws, size_t ws_size,
                              hipStream_t stream)
{
    const float* Y   = (const float*)d_in[0];
    const float* em  = (const float*)d_in[1];
    const int*   sl  = (const int*)d_in[2];
    const float* W1  = (const float*)d_in[3];
    const float* b1  = (const float*)d_in[4];
    const float* W2  = (const float*)d_in[5];
    const float* b2  = (const float*)d_in[6];
    const float* W3  = (const float*)d_in[7];
    const float* b3  = (const float*)d_in[8];
    float* out = (float*)d_out;
    char* ws = (char*)d_ws;

    __bf16* W1T  = (__bf16*)(ws + OFF_W1T);
    __bf16* W23B = (__bf16*)(ws + OFF_W23B);
    u16*    ts   = (u16*)(ws + OFF_TS);
    float*  jwT  = (float*)(ws + OFF_JWT);
    float*  p0   = (float*)(ws + OFF_P0);

    prep_kernel<<<164, 256, 0, stream>>>(W1, W2, W3, W1T, W23B);
    dim3 g1(128, 4);
    gemm1_kernel<<<g1, 256, 0, stream>>>(Y, W1T, b1, ts);
    band_kernel<<<128, 256, 0, stream>>>(ts, (const u16*)W23B, b2, b3, jwT, p0);
    recur_kernel<<<128, 64, 0, stream>>>(jwT, p0, em, sl, out);
}